// Round 16
// baseline (255.200 us; speedup 1.0000x reference)
//
#include <hip/hip_runtime.h>
#include <math.h>

// FilterMLPBlock: out = LN_D( irfft(rfft(x,ortho)*w,ortho) + x ),  B=4096,S=64,D=256
// R16 = R11 (130.0us, best) + 4 batches per block (grid 1024).
//   h = C2 * ((W+1) o (C1 * x))        [residual folded: C2*C1 = I]
//   GEMM1/GEMM2: K=64 plain-bf16, v_cvt_pk_bf16_f32 packing.
// Theory: stores fire only in the last ~15% of each block's life and blocks
// move in lockstep -> write bursts (observed write rate 2 TB/s vs fill's 7).
// Batch loop overlaps batch bb's store drain with bb+1's loads/compute,
// end-drain happens once, A-tables L1-hot for batches 1-3, grid = exactly
// 4 blocks/CU x 256 CU in one round.
// mr/ps2/pq2 live OUTSIDE the V/psum overlay so the loop needs no extra
// barrier (V-writes of iter bb+1 only overwrite regions whose readers are
// all behind iter bb's 3rd barrier).
// Tripwire: WRITE_SIZE > 262 MB => spill => revert.

typedef __attribute__((ext_vector_type(8))) short short8;
typedef __attribute__((ext_vector_type(4))) float f32x4;
typedef __attribute__((ext_vector_type(4))) unsigned int u32x4;
typedef __attribute__((ext_vector_type(2))) unsigned int u32x2;

#define VROW 144   // V row stride bytes (64 bf16 + 16 pad), 16B-aligned b128

__device__ __forceinline__ unsigned short bf16rn(float v) {
    unsigned u = __float_as_uint(v);
    u += 0x7fffu + ((u >> 16) & 1u);
    return (unsigned short)(u >> 16);
}
// hardware packed convert: dst = (bf16(a) in lo16, bf16(b) in hi16), RNE
__device__ __forceinline__ unsigned cvtpk(float a, float b) {
    unsigned r;
    asm("v_cvt_pk_bf16_f32 %0, %1, %2" : "=v"(r) : "v"(a), "v"(b));
    return r;
}

// A tables in ws: A1 = 8 frags (K=64, C1), 8 KB; A2 = 8 frags (K=64, C2),
// 8 KB at short-offset 4096. Frag layout (HW-verified R8-R15 passing):
// lane l, j=0..7: m = mi*16 + (l&15), k = kt*32 + 8*(l>>4) + j.
__global__ void pack_A_kernel(unsigned short* __restrict__ apack) {
    const int bid  = blockIdx.x;         // 0..15
    const int lane = threadIdx.x;        // 0..63
    const float step = 6.28318530717958647692f / 64.f;
    const int fid = bid & 7;
    const int kt = fid >> 2, mi = fid & 3;
    const int m = mi * 16 + (lane & 15);
    if (bid < 8) {                       // A1 = C1 (rfft, ortho, re||im rows)
        unsigned short* dst = apack + ((size_t)fid * 64 + lane) * 8;
        #pragma unroll
        for (int j = 0; j < 8; ++j) {
            const int t = kt * 32 + 8 * (lane >> 4) + j;    // time index
            float val;
            if (m <= 32) val =  cosf(step * (float)((m * t) & 63)) * 0.125f;
            else         val = -sinf(step * (float)(((m - 32) * t) & 63)) * 0.125f;
            dst[j] = bf16rn(val);
        }
    } else {                             // A2 = C2 (irfft, ortho)
        unsigned short* dst = apack + 4096 + ((size_t)fid * 64 + lane) * 8;
        #pragma unroll
        for (int j = 0; j < 8; ++j) {
            const int c = kt * 32 + 8 * (lane >> 4) + j;    // V-row index
            float val;
            if (c == 0)       val = 0.125f;
            else if (c == 32) val = (m & 1) ? -0.125f : 0.125f;
            else if (c < 32)  val =  0.25f * cosf(step * (float)((c * m) & 63));
            else              val = -0.25f * sinf(step * (float)(((c - 32) * m) & 63));
            dst[j] = bf16rn(val);
        }
    }
}

#define MFMA(A, B, C) __builtin_amdgcn_mfma_f32_16x16x32_bf16( \
    __builtin_bit_cast(short8, A), (B), (C), 0, 0, 0)

#define BPB 4      // batches per block

__global__ __launch_bounds__(256, 4)
void fft_ln_kernel(const float* __restrict__ x,
                   const float* __restrict__ cw,
                   const float* __restrict__ gamma,
                   const float* __restrict__ beta,
                   const unsigned short* __restrict__ apack,
                   float* __restrict__ out) {
    __shared__ __align__(16) char smem[4 * 64 * VROW];  // 36.9 KB: V; psum/psq overlay
    __shared__ float ps2[64 * 5];                       // outside overlay:
    __shared__ float pq2[64 * 5];                       //  loop needs no extra barrier
    __shared__ float mr[128];                           // [64][2] mean, rstd
    const int tid = threadIdx.x, lane = tid & 63, wv = tid >> 6;
    const int hi = lane >> 4, lm = lane & 15;
    const int dbase = wv * 64;
    const u32x4* __restrict__ ap1 = (const u32x4*)apack;
    const u32x4* __restrict__ ap2 = (const u32x4*)(apack + 4096);

    #pragma unroll 1
    for (int bb = 0; bb < BPB; ++bb) {
        const int b = blockIdx.x * BPB + bb;
        const float* __restrict__ xb = x + (size_t)b * 16384;

        f32x4 acc[16];                       // [mi*4+ni]
        #pragma unroll
        for (int i = 0; i < 16; ++i) acc[i] = (f32x4)0.f;

        // ---- GEMM1: U = C1*x, K=64 plain bf16; x packed by v_cvt_pk ----
        #pragma unroll
        for (int kt = 0; kt < 2; ++kt) {
            const u32x4 af0 = ap1[(kt * 4 + 0) * 64 + lane];
            const u32x4 af1 = ap1[(kt * 4 + 1) * 64 + lane];
            const u32x4 af2 = ap1[(kt * 4 + 2) * 64 + lane];
            const u32x4 af3 = ap1[(kt * 4 + 3) * 64 + lane];
            const float* __restrict__ xp = xb + (kt * 32 + 8 * hi) * 256 + dbase + lm;
            #pragma unroll
            for (int ni = 0; ni < 4; ++ni) {
                float xv[8];
                #pragma unroll
                for (int j = 0; j < 8; ++j) xv[j] = xp[j * 256 + ni * 16];
                u32x4 bw;
                bw[0] = cvtpk(xv[0], xv[1]);
                bw[1] = cvtpk(xv[2], xv[3]);
                bw[2] = cvtpk(xv[4], xv[5]);
                bw[3] = cvtpk(xv[6], xv[7]);
                const short8 bbv = __builtin_bit_cast(short8, bw);
                acc[0 * 4 + ni] = MFMA(af0, bbv, acc[0 * 4 + ni]);
                acc[1 * 4 + ni] = MFMA(af1, bbv, acc[1 * 4 + ni]);
                acc[2 * 4 + ni] = MFMA(af2, bbv, acc[2 * 4 + ni]);
                acc[3 * 4 + ni] = MFMA(af3, bbv, acc[3 * 4 + ni]);
            }
        }

        // ---- filter multiply + residual fold: V = (W+1) o U (fp32) ----
        #pragma unroll
        for (int mi = 0; mi < 2; ++mi)
        #pragma unroll
        for (int ni = 0; ni < 4; ++ni) {
            const int d = dbase + ni * 16 + lm;
            #pragma unroll
            for (int r = 0; r < 4; ++r) {
                const int f = mi * 16 + hi * 4 + r;
                const float2 wc = *(const float2*)(cw + ((size_t)(f * 256 + d)) * 2);
                const float wr1 = wc.x + 1.f;
                const float Ure = acc[mi * 4 + ni][r];
                const float Uim = acc[(mi + 2) * 4 + ni][r];
                float Vre = Ure * wr1 - Uim * wc.y;
                float Vim = Ure * wc.y + Uim * wr1;
                if (mi == 0 && r == 0) {             // f==0 lanes: DC & Nyquist
                    const float w32 = cw[(32 * 256 + d) * 2] + 1.f;
                    if (hi == 0) { Vre = Ure * wr1; Vim = Uim * w32; }
                }
                acc[mi * 4 + ni][r]       = Vre;
                acc[(mi + 2) * 4 + ni][r] = Vim;
            }
        }

        // ---- V -> bf16 LDS [dl][f] via cvt_pk; wave-private; stride 144 B ----
        char* vb = smem + wv * 64 * VROW;
        #pragma unroll
        for (int mi = 0; mi < 4; ++mi)
        #pragma unroll
        for (int ni = 0; ni < 4; ++ni) {
            const f32x4 a4 = acc[mi * 4 + ni];
            u32x2 p;
            p[0] = cvtpk(a4[0], a4[1]);
            p[1] = cvtpk(a4[2], a4[3]);
            const int dl = ni * 16 + lm;
            *(u32x2*)(vb + dl * VROW + mi * 32 + hi * 8) = p;   // f0 = mi*16+hi*4
        }

        // ---- GEMM2: h = C2 * V, K=64 plain bf16 (acc reused, re-zeroed) ----
        #pragma unroll
        for (int i = 0; i < 16; ++i) acc[i] = (f32x4)0.f;
        #pragma unroll
        for (int kt = 0; kt < 2; ++kt) {
            const u32x4 af0 = ap2[(kt * 4 + 0) * 64 + lane];
            const u32x4 af1 = ap2[(kt * 4 + 1) * 64 + lane];
            const u32x4 af2 = ap2[(kt * 4 + 2) * 64 + lane];
            const u32x4 af3 = ap2[(kt * 4 + 3) * 64 + lane];
            #pragma unroll
            for (int ni = 0; ni < 4; ++ni) {
                const int dl = ni * 16 + lm;
                const u32x4 bw = *(const u32x4*)(vb + dl * VROW + kt * 64 + hi * 16);
                const short8 bbv = __builtin_bit_cast(short8, bw);
                acc[0 * 4 + ni] = MFMA(af0, bbv, acc[0 * 4 + ni]);
                acc[1 * 4 + ni] = MFMA(af1, bbv, acc[1 * 4 + ni]);
                acc[2 * 4 + ni] = MFMA(af2, bbv, acc[2 * 4 + ni]);
                acc[3 * 4 + ni] = MFMA(af3, bbv, acc[3 * 4 + ni]);
            }
        }

        // ---- LayerNorm over d: fp32 partials [64][66] overlay the V region ----
        __syncthreads();                       // all waves done reading their V
        float* psum = (float*)smem;            // [64][66]
        float* psq  = (float*)smem + 64 * 66;  // 33.8 KB <= 36.9 KB
        #pragma unroll
        for (int mi = 0; mi < 4; ++mi)
        #pragma unroll
        for (int r = 0; r < 4; ++r) {
            float s1 = 0.f, s2 = 0.f;
            #pragma unroll
            for (int ni = 0; ni < 4; ++ni) {
                const float v = acc[mi * 4 + ni][r];
                s1 += v;
                s2 = fmaf(v, v, s2);
            }
            const int row = mi * 16 + hi * 4 + r;
            psum[row * 66 + wv * 16 + lm] = s1;
            psq [row * 66 + wv * 16 + lm] = s2;
        }
        __syncthreads();
        {   // parallel combine: thread (row = tid&63, g = wv) sums 16 cols
            const int row = tid & 63;
            float s1 = 0.f, s2 = 0.f;
            #pragma unroll
            for (int j = 0; j < 16; ++j) {
                s1 += psum[row * 66 + wv * 16 + j];
                s2 += psq [row * 66 + wv * 16 + j];
            }
            ps2[row * 5 + wv] = s1;
            pq2[row * 5 + wv] = s2;
        }
        __syncthreads();
        if (tid < 64) {
            const float s1 = ps2[tid * 5] + ps2[tid * 5 + 1] + ps2[tid * 5 + 2] + ps2[tid * 5 + 3];
            const float s2 = pq2[tid * 5] + pq2[tid * 5 + 1] + pq2[tid * 5 + 2] + pq2[tid * 5 + 3];
            const float mean = s1 * (1.f / 256.f);
            const float var  = s2 * (1.f / 256.f) - mean * mean;
            mr[tid * 2 + 0] = mean;
            mr[tid * 2 + 1] = rsqrtf(var + 1e-12f);
        }
        __syncthreads();

        // ---- normalize + affine + store (64B segments per 16-lane group) ----
        f32x4 gv, bv;
        #pragma unroll
        for (int ni = 0; ni < 4; ++ni) {
            gv[ni] = gamma[dbase + ni * 16 + lm];
            bv[ni] = beta [dbase + ni * 16 + lm];
        }
        float* __restrict__ ob = out + (size_t)b * 16384;
        #pragma unroll
        for (int mi = 0; mi < 4; ++mi)
        #pragma unroll
        for (int r = 0; r < 4; ++r) {
            const int row = mi * 16 + hi * 4 + r;
            const float m  = mr[row * 2 + 0];
            const float rs = mr[row * 2 + 1];
            #pragma unroll
            for (int ni = 0; ni < 4; ++ni)
                ob[row * 256 + dbase + ni * 16 + lm] =
                    (acc[mi * 4 + ni][r] - m) * rs * gv[ni] + bv[ni];
        }
        // stores are fire-and-forget: they drain while the next batch's
        // x-loads and GEMM1 issue. mr/ps2/pq2 are outside the V overlay, so
        // no extra barrier is needed at the loop boundary (see header note).
    }
}

extern "C" void kernel_launch(void* const* d_in, const int* in_sizes, int n_in,
                              void* d_out, int out_size, void* d_ws, size_t ws_size,
                              hipStream_t stream) {
    const float* x     = (const float*)d_in[0];
    const float* cw    = (const float*)d_in[1];   // [1,33,256,2]
    const float* gamma = (const float*)d_in[2];
    const float* beta  = (const float*)d_in[3];
    float* outp = (float*)d_out;
    unsigned short* apack = (unsigned short*)d_ws;   // 16 KB fragment tables

    pack_A_kernel<<<16, 64, 0, stream>>>(apack);
    fft_ln_kernel<<<4096 / BPB, 256, 0, stream>>>(x, cw, gamma, beta, apack, outp);
}

// Round 17
// 132.199 us; speedup vs baseline: 1.9304x; 1.9304x over previous
//
#include <hip/hip_runtime.h>
#include <math.h>

// FilterMLPBlock: out = LN_D( irfft(rfft(x,ortho)*w,ortho) + x ),  B=4096,S=64,D=256
// R17 = R11 (130.0us, best) with GEMM2 re-mapped N-split -> M-split so the
// LayerNorm is wave-local (shuffle-only, zero LDS, zero extra barriers).
//   h = C2 * ((W+1) o (C1 * x))        [residual folded: C2*C1 = I]
//   GEMM1/GEMM2: K=64 plain-bf16, v_cvt_pk_bf16_f32 packing.
// R16 post-mortem: batch loop spilled (WRITE 354MB) + shrank grid; reverted.
// R17 change: wave wv computes h rows [16wv,16wv+16) x ALL 256 d (16 ni
// frags, 2 A2 frags, same 32 MFMA). Output row 16wv+4hi+r lives entirely in
// one 16-lane group -> LN = 15 reg adds + 4 shfl_xor(width16). V becomes
// block-shared (same 36.9 KB); ONE barrier (after V-write) replaces R11's
// three LN barriers + psum/psq/mr LDS round-trips.
// Tripwire: WRITE_SIZE > 262 MB => spill => revert.

typedef __attribute__((ext_vector_type(8))) short short8;
typedef __attribute__((ext_vector_type(4))) float f32x4;
typedef __attribute__((ext_vector_type(4))) unsigned int u32x4;
typedef __attribute__((ext_vector_type(2))) unsigned int u32x2;

#define VROW 144   // V row stride bytes (64 bf16 + 16 pad), 16B-aligned b128

__device__ __forceinline__ unsigned short bf16rn(float v) {
    unsigned u = __float_as_uint(v);
    u += 0x7fffu + ((u >> 16) & 1u);
    return (unsigned short)(u >> 16);
}
// hardware packed convert: dst = (bf16(a) in lo16, bf16(b) in hi16), RNE
__device__ __forceinline__ unsigned cvtpk(float a, float b) {
    unsigned r;
    asm("v_cvt_pk_bf16_f32 %0, %1, %2" : "=v"(r) : "v"(a), "v"(b));
    return r;
}

// A tables in ws: A1 = 8 frags (K=64, C1), 8 KB; A2 = 8 frags (K=64, C2),
// 8 KB at short-offset 4096. Frag layout (HW-verified R8-R16 passing):
// lane l, j=0..7: m = mi*16 + (l&15), k = kt*32 + 8*(l>>4) + j.
__global__ void pack_A_kernel(unsigned short* __restrict__ apack) {
    const int bid  = blockIdx.x;         // 0..15
    const int lane = threadIdx.x;        // 0..63
    const float step = 6.28318530717958647692f / 64.f;
    const int fid = bid & 7;
    const int kt = fid >> 2, mi = fid & 3;
    const int m = mi * 16 + (lane & 15);
    if (bid < 8) {                       // A1 = C1 (rfft, ortho, re||im rows)
        unsigned short* dst = apack + ((size_t)fid * 64 + lane) * 8;
        #pragma unroll
        for (int j = 0; j < 8; ++j) {
            const int t = kt * 32 + 8 * (lane >> 4) + j;    // time index
            float val;
            if (m <= 32) val =  cosf(step * (float)((m * t) & 63)) * 0.125f;
            else         val = -sinf(step * (float)(((m - 32) * t) & 63)) * 0.125f;
            dst[j] = bf16rn(val);
        }
    } else {                             // A2 = C2 (irfft, ortho)
        unsigned short* dst = apack + 4096 + ((size_t)fid * 64 + lane) * 8;
        #pragma unroll
        for (int j = 0; j < 8; ++j) {
            const int c = kt * 32 + 8 * (lane >> 4) + j;    // V-row index
            float val;
            if (c == 0)       val = 0.125f;
            else if (c == 32) val = (m & 1) ? -0.125f : 0.125f;
            else if (c < 32)  val =  0.25f * cosf(step * (float)((c * m) & 63));
            else              val = -0.25f * sinf(step * (float)(((c - 32) * m) & 63));
            dst[j] = bf16rn(val);
        }
    }
}

#define MFMA(A, B, C) __builtin_amdgcn_mfma_f32_16x16x32_bf16( \
    __builtin_bit_cast(short8, A), (B), (C), 0, 0, 0)

__global__ __launch_bounds__(256, 4)
void fft_ln_kernel(const float* __restrict__ x,
                   const float* __restrict__ cw,
                   const float* __restrict__ gamma,
                   const float* __restrict__ beta,
                   const unsigned short* __restrict__ apack,
                   float* __restrict__ out) {
    __shared__ __align__(16) char smem[256 * VROW];     // block-shared V, 36.9 KB
    const int tid = threadIdx.x, lane = tid & 63, wv = tid >> 6;
    const int hi = lane >> 4, lm = lane & 15;
    const int b = blockIdx.x, dbase = wv * 64;
    const float* __restrict__ xb = x + (size_t)b * 16384;
    const u32x4* __restrict__ ap1 = (const u32x4*)apack;
    const u32x4* __restrict__ ap2 = (const u32x4*)(apack + 4096);

    f32x4 acc[16];                       // GEMM1: [mi*4+ni]; GEMM2: [ni]
    #pragma unroll
    for (int i = 0; i < 16; ++i) acc[i] = (f32x4)0.f;

    // ---- GEMM1: U = C1*x (M=64 x N=64/wave), K=64 bf16, cvt_pk packing ----
    #pragma unroll
    for (int kt = 0; kt < 2; ++kt) {
        const u32x4 af0 = ap1[(kt * 4 + 0) * 64 + lane];
        const u32x4 af1 = ap1[(kt * 4 + 1) * 64 + lane];
        const u32x4 af2 = ap1[(kt * 4 + 2) * 64 + lane];
        const u32x4 af3 = ap1[(kt * 4 + 3) * 64 + lane];
        const float* __restrict__ xp = xb + (kt * 32 + 8 * hi) * 256 + dbase + lm;
        #pragma unroll
        for (int ni = 0; ni < 4; ++ni) {
            float xv[8];
            #pragma unroll
            for (int j = 0; j < 8; ++j) xv[j] = xp[j * 256 + ni * 16];
            u32x4 bw;
            bw[0] = cvtpk(xv[0], xv[1]);
            bw[1] = cvtpk(xv[2], xv[3]);
            bw[2] = cvtpk(xv[4], xv[5]);
            bw[3] = cvtpk(xv[6], xv[7]);
            const short8 bbv = __builtin_bit_cast(short8, bw);
            acc[0 * 4 + ni] = MFMA(af0, bbv, acc[0 * 4 + ni]);
            acc[1 * 4 + ni] = MFMA(af1, bbv, acc[1 * 4 + ni]);
            acc[2 * 4 + ni] = MFMA(af2, bbv, acc[2 * 4 + ni]);
            acc[3 * 4 + ni] = MFMA(af3, bbv, acc[3 * 4 + ni]);
        }
    }

    // ---- filter multiply + residual fold: V = (W+1) o U (fp32, lane-local) ----
    #pragma unroll
    for (int mi = 0; mi < 2; ++mi)
    #pragma unroll
    for (int ni = 0; ni < 4; ++ni) {
        const int d = dbase + ni * 16 + lm;
        #pragma unroll
        for (int r = 0; r < 4; ++r) {
            const int f = mi * 16 + hi * 4 + r;
            const float2 wc = *(const float2*)(cw + ((size_t)(f * 256 + d)) * 2);
            const float wr1 = wc.x + 1.f;
            const float Ure = acc[mi * 4 + ni][r];
            const float Uim = acc[(mi + 2) * 4 + ni][r];
            float Vre = Ure * wr1 - Uim * wc.y;
            float Vim = Ure * wc.y + Uim * wr1;
            if (mi == 0 && r == 0) {                 // f==0 lanes: DC & Nyquist
                const float w32 = cw[(32 * 256 + d) * 2] + 1.f;
                if (hi == 0) { Vre = Ure * wr1; Vim = Uim * w32; }
            }
            acc[mi * 4 + ni][r]       = Vre;
            acc[(mi + 2) * 4 + ni][r] = Vim;
        }
    }

    // ---- V -> bf16 block-shared LDS [d 0..255][f], row stride 144 B ----
    #pragma unroll
    for (int mi = 0; mi < 4; ++mi)
    #pragma unroll
    for (int ni = 0; ni < 4; ++ni) {
        const f32x4 a4 = acc[mi * 4 + ni];
        u32x2 p;
        p[0] = cvtpk(a4[0], a4[1]);
        p[1] = cvtpk(a4[2], a4[3]);
        const int dg = dbase + ni * 16 + lm;         // global d row
        *(u32x2*)(smem + dg * VROW + mi * 32 + hi * 8) = p;  // f0 = mi*16+hi*4
    }
    __syncthreads();                     // the ONLY barrier

    // ---- GEMM2 (M-split): h rows [16wv,16wv+16) x all 256 d; 2 A2 frags ----
    #pragma unroll
    for (int i = 0; i < 16; ++i) acc[i] = (f32x4)0.f;
    #pragma unroll
    for (int kt = 0; kt < 2; ++kt) {
        const u32x4 af = ap2[(kt * 4 + wv) * 64 + lane];   // mi = wv
        #pragma unroll
        for (int ni = 0; ni < 16; ++ni) {
            const int dg = ni * 16 + lm;
            const u32x4 bw = *(const u32x4*)(smem + dg * VROW + kt * 64 + hi * 16);
            const short8 bbv = __builtin_bit_cast(short8, bw);
            acc[ni] = MFMA(af, bbv, acc[ni]);
        }
    }

    // ---- LayerNorm: rows are wave-local -> in-register + shfl_xor(16) ----
    // element (ni, r) of acc: row = 16*wv + 4*hi + r, d = ni*16 + lm.
    float gv[16], bv[16];
    #pragma unroll
    for (int ni = 0; ni < 16; ++ni) {
        gv[ni] = gamma[ni * 16 + lm];
        bv[ni] = beta [ni * 16 + lm];
    }
    float* __restrict__ ob = out + (size_t)b * 16384;
    #pragma unroll
    for (int r = 0; r < 4; ++r) {
        float s1 = 0.f, s2 = 0.f;
        #pragma unroll
        for (int ni = 0; ni < 16; ++ni) {
            const float v = acc[ni][r];
            s1 += v;
            s2 = fmaf(v, v, s2);
        }
        #pragma unroll
        for (int m = 1; m < 16; m <<= 1) {           // reduce across 16-lane group
            s1 += __shfl_xor(s1, m, 16);
            s2 += __shfl_xor(s2, m, 16);
        }
        const float mean = s1 * (1.f / 256.f);
        const float var  = s2 * (1.f / 256.f) - mean * mean;
        const float rstd = rsqrtf(var + 1e-12f);
        const int row = 16 * wv + 4 * hi + r;
        #pragma unroll
        for (int ni = 0; ni < 16; ++ni)
            ob[row * 256 + ni * 16 + lm] =
                (acc[ni][r] - mean) * rstd * gv[ni] + bv[ni];
    }
}

extern "C" void kernel_launch(void* const* d_in, const int* in_sizes, int n_in,
                              void* d_out, int out_size, void* d_ws, size_t ws_size,
                              hipStream_t stream) {
    const float* x     = (const float*)d_in[0];
    const float* cw    = (const float*)d_in[1];   // [1,33,256,2]
    const float* gamma = (const float*)d_in[2];
    const float* beta  = (const float*)d_in[3];
    float* outp = (float*)d_out;
    unsigned short* apack = (unsigned short*)d_ws;   // 16 KB fragment tables

    pack_A_kernel<<<16, 64, 0, stream>>>(apack);
    fft_ln_kernel<<<4096, 256, 0, stream>>>(x, cw, gamma, beta, apack, outp);
}